// Round 7
// baseline (123.136 us; speedup 1.0000x reference)
//
#include <hip/hip_runtime.h>

#define D 512      // view dim / d_out
#define B 4096     // batch
#define R 32       // TT rank
#define AB 1024    // R*R rows of reshaped core GEMM

typedef unsigned short ushort_t;
typedef __attribute__((ext_vector_type(8))) short bf16x8;
typedef __attribute__((ext_vector_type(4))) float f32x4;

__device__ __forceinline__ ushort_t f2bf(float f) {
  uint32_t u = __builtin_bit_cast(uint32_t, f);
  u = (u + 0x7FFFu + ((u >> 16) & 1u)) >> 16;   // RNE
  return (ushort_t)u;
}
__device__ __forceinline__ float bf2f(ushort_t h) {
  uint32_t u = ((uint32_t)h) << 16;
  return __builtin_bit_cast(float, u);
}
__device__ __forceinline__ void gload_lds16(const void* g, void* lds) {
  __builtin_amdgcn_global_load_lds(
      (const __attribute__((address_space(1))) unsigned int*)g,
      (__attribute__((address_space(3))) unsigned int*)lds, 16, 0, 0);
}

// ---------------------------------------------------------------------------
// K1: prep — one flat-grid kernel:
//   bid <  1024 : transpose X_v fp32 [d][n] -> Xt bf16 [v][n][d]  (v = bid>>9)
//   1024..1087  : pack core1/core2 [a][d][b] -> Apack[j][a*32+b][d] bf16
//   1088..1215  : m2buf[n][c] = sum_d core3[c][d]*X2[d][n]  (fp32, 32 n/block)
// ---------------------------------------------------------------------------
__global__ __launch_bounds__(256) void prep(
    const float* __restrict__ X0, const float* __restrict__ X1,
    const float* __restrict__ X2, const float* __restrict__ c1,
    const float* __restrict__ c2, const float* __restrict__ c3,
    ushort_t* __restrict__ Xt, ushort_t* __restrict__ Apack,
    float* __restrict__ m2buf)
{
  __shared__ __align__(16) char smem[33280];
  const int bid = blockIdx.x, tid = threadIdx.x;

  if (bid < 1024) {
    // ---- transpose: 64x64 tile ----
    float (*T)[65] = (float(*)[65])smem;          // [64][65]
    const int v = bid >> 9, tile = bid & 511;
    const float* __restrict__ X = v ? X1 : X0;
    ushort_t* __restrict__ O = Xt + (size_t)v * B * D;
    const int n0 = (tile & 63) * 64, d0 = (tile >> 6) * 64;
#pragma unroll
    for (int i = 0; i < 16; ++i) {
      int e = i * 256 + tid;
      T[e >> 6][e & 63] = X[(size_t)(d0 + (e >> 6)) * B + n0 + (e & 63)];
    }
    __syncthreads();
#pragma unroll
    for (int i = 0; i < 2; ++i) {
      int ch = i * 256 + tid;                // 512 chunks
      int nr = ch >> 3, dc = (ch & 7) * 8;
      ushort_t w[8];
#pragma unroll
      for (int q = 0; q < 8; ++q) w[q] = f2bf(T[dc + q][nr]);
      *(bf16x8*)&O[(size_t)(n0 + nr) * D + d0 + dc] = *(bf16x8*)w;
    }
  } else if (bid < 1088) {
    // ---- pack core1/core2 ----
    ushort_t (*T)[D + 8] = (ushort_t(*)[D + 8])smem;   // [32][520]
    const int ja = bid - 1024, j = ja >> 5, a = ja & 31;
    const float* __restrict__ c = j ? c2 : c1;
#pragma unroll
    for (int i = 0; i < 64; ++i) {
      int e = i * 256 + tid;                 // e = d*32 + b, coalesced source
      T[e & 31][e >> 5] = f2bf(c[(size_t)a * (D * R) + e]);
    }
    __syncthreads();
#pragma unroll
    for (int i = 0; i < 8; ++i) {
      int ch = i * 256 + tid;                // 2048 16B chunks
      int b = ch >> 6, off = (ch & 63) * 8;
      ushort_t w[8];
#pragma unroll
      for (int q = 0; q < 8; ++q) w[q] = T[b][off + q];
      *(bf16x8*)&Apack[((size_t)j * AB + a * 32 + b) * D + off] = *(bf16x8*)w;
    }
  } else {
    // ---- m2: 32 samples per block, fp32 ----
    float (*Xs)[32] = (float(*)[32])smem;               // [64][32]
    float (*mst)[36] = (float(*)[36])(smem + 64 * 32 * 4);  // [32][36]
    const int n0 = (bid - 1088) * 32;
    const int cc = tid >> 3, nq = tid & 7;
    float acc[4] = {};
    for (int d0 = 0; d0 < D; d0 += 64) {
      __syncthreads();
#pragma unroll
      for (int i = 0; i < 8; ++i) {
        int e = i * 256 + tid;
        Xs[e >> 5][e & 31] = X2[(size_t)(d0 + (e >> 5)) * B + n0 + (e & 31)];
      }
      __syncthreads();
#pragma unroll 4
      for (int d4 = 0; d4 < 64; d4 += 4) {
        float4 w4 = *(const float4*)&c3[(size_t)cc * D + d0 + d4];
        float ww[4] = {w4.x, w4.y, w4.z, w4.w};
#pragma unroll
        for (int dd = 0; dd < 4; ++dd) {
          float4 x = *(const float4*)&Xs[d4 + dd][nq * 4];
          acc[0] += ww[dd] * x.x; acc[1] += ww[dd] * x.y;
          acc[2] += ww[dd] * x.z; acc[3] += ww[dd] * x.w;
        }
      }
    }
    __syncthreads();
#pragma unroll
    for (int i = 0; i < 4; ++i) mst[nq * 4 + i][cc] = acc[i];
    __syncthreads();
    {
      int nl = tid >> 3, c4 = (tid & 7) * 4;
      float4 v = {mst[nl][c4], mst[nl][c4 + 1], mst[nl][c4 + 2], mst[nl][c4 + 3]};
      *(float4*)&m2buf[(size_t)(n0 + nl) * R + c4] = v;
    }
  }
}

// ---------------------------------------------------------------------------
// K2: MFMA GEMM (bf16 16x16x32), 128x128 tile, BK=32, 4 waves, dbuf
// global_load_lds, XOR-swizzled LDS.
//   bid<256 : view0 -> full Mt0[n][row] (LDS-staged coalesced epilogue)
//   bid>=256: view1 -> fused t-reduction: t[b,n] = sum_c M1tile[n][b*32+c]*m2[c,n]
// ---------------------------------------------------------------------------
__global__ __launch_bounds__(256) void gemm_mfma(
    const ushort_t* __restrict__ Apack, const ushort_t* __restrict__ Xt,
    const float* __restrict__ m2buf, ushort_t* __restrict__ Mt0,
    float* __restrict__ tbuf)
{
  __shared__ __align__(16) ushort_t smem[17408];   // 34.8 KB
  ushort_t* As0 = smem;            // Xt tile buf0: [128 n][32 k] swizzled
  ushort_t* As1 = smem + 4096;
  ushort_t* Bs0 = smem + 8192;     // core tile
  ushort_t* Bs1 = smem + 12288;

  const int bid = blockIdx.x;
  const int j = (bid >= 256);
  const int w = bid & 255, rb = w >> 5, nb = w & 31;
  const ushort_t* __restrict__ Ag = Xt + (size_t)j * B * D;
  const ushort_t* __restrict__ Bg = Apack + (size_t)j * AB * D;

  const int tid = threadIdx.x;
  const int lane = tid & 63, wid = tid >> 6;
  const int wr = wid >> 1, wc = wid & 1;
  const int nBase = nb * 128;   // over B=4096
  const int rBase = rb * 128;   // over AB=1024

  // staging map: 16B unit t -> LDS (row=t>>2, slot u'=t&3); src u = u'^(row&3)
  const int t0 = wid * 128 + lane, t1 = t0 + 64;
  const int r0 = t0 >> 2, u0 = (t0 & 3) ^ (r0 & 3);
  const int r1 = t1 >> 2, u1 = (t1 & 3) ^ (r1 & 3);
  const ushort_t* gA0 = Ag + (size_t)(nBase + r0) * D + u0 * 8;
  const ushort_t* gA1 = Ag + (size_t)(nBase + r1) * D + u1 * 8;
  const ushort_t* gB0 = Bg + (size_t)(rBase + r0) * D + u0 * 8;
  const ushort_t* gB1 = Bg + (size_t)(rBase + r1) * D + u1 * 8;
  const int lq0 = wid * 1024, lq1 = wid * 1024 + 512;   // element offsets

  // frag read offsets: logical (row, u=lane>>4) -> slot u^(row&3)
  int aoff[4], boff[4];
#pragma unroll
  for (int m = 0; m < 4; ++m) {
    int row = wr * 64 + m * 16 + (lane & 15);
    aoff[m] = row * 32 + (((lane >> 4) ^ (row & 3)) * 8);
  }
#pragma unroll
  for (int n = 0; n < 4; ++n) {
    int col = wc * 64 + n * 16 + (lane & 15);
    boff[n] = col * 32 + (((lane >> 4) ^ (col & 3)) * 8);
  }

  f32x4 acc[4][4] = {};

  auto stage = [&](ushort_t* Asb, ushort_t* Bsb, int k0) {
    gload_lds16(gA0 + k0, Asb + lq0);
    gload_lds16(gA1 + k0, Asb + lq1);
    gload_lds16(gB0 + k0, Bsb + lq0);
    gload_lds16(gB1 + k0, Bsb + lq1);
  };
  auto compute = [&](const ushort_t* Asb, const ushort_t* Bsb) {
    bf16x8 a[4], b[4];
#pragma unroll
    for (int m = 0; m < 4; ++m) a[m] = *(const bf16x8*)&Asb[aoff[m]];
#pragma unroll
    for (int n = 0; n < 4; ++n) b[n] = *(const bf16x8*)&Bsb[boff[n]];
#pragma unroll
    for (int m = 0; m < 4; ++m)
#pragma unroll
      for (int n = 0; n < 4; ++n)
        acc[m][n] = __builtin_amdgcn_mfma_f32_16x16x32_bf16(a[m], b[n], acc[m][n], 0, 0, 0);
  };

  stage(As0, Bs0, 0);
  __syncthreads();
#pragma unroll 1
  for (int kp = 0; kp < 8; ++kp) {
    stage(As1, Bs1, kp * 64 + 32);        // prefetch odd tile
    compute(As0, Bs0);
    __syncthreads();
    if (kp < 7) stage(As0, Bs0, kp * 64 + 64);  // prefetch next even tile
    compute(As1, Bs1);
    __syncthreads();
  }

  // stage acc -> LDS tile T[128 n][128 row] (pad 8), bf16
#define TLD 136
  ushort_t* T = smem;
  const int qn = (lane >> 4) << 2;
#pragma unroll
  for (int m = 0; m < 4; ++m)
#pragma unroll
    for (int nn = 0; nn < 4; ++nn) {
      int nl = wr * 64 + m * 16 + qn;
      int rl = wc * 64 + nn * 16 + (lane & 15);
#pragma unroll
      for (int r = 0; r < 4; ++r)
        T[(nl + r) * TLD + rl] = f2bf(acc[m][nn][r]);
    }
  __syncthreads();

  if (j == 0) {
    // view0: coalesced [n][row] stores
#pragma unroll
    for (int i = 0; i < 8; ++i) {
      int nl = i * 16 + (tid >> 4);
      int rl = (tid & 15) * 8;
      bf16x8 v = *(const bf16x8*)&T[nl * TLD + rl];
      *(bf16x8*)&Mt0[(size_t)(nBase + nl) * AB + rBase + rl] = v;
    }
  } else {
    // view1: fused t-reduction. thread -> (b_local = (tid>>7)*2+bb, n = tid&127)
    const int nloc = tid & 127, bh = tid >> 7;
    const int ng = nBase + nloc;
    float m2f[32];
#pragma unroll
    for (int q = 0; q < 8; ++q) {
      float4 v = *(const float4*)&m2buf[(size_t)ng * R + q * 4];
      m2f[q * 4 + 0] = v.x; m2f[q * 4 + 1] = v.y;
      m2f[q * 4 + 2] = v.z; m2f[q * 4 + 3] = v.w;
    }
#pragma unroll
    for (int bb = 0; bb < 2; ++bb) {
      int bl = bh * 2 + bb;
      float t = 0.f;
#pragma unroll
      for (int q = 0; q < 4; ++q) {
        bf16x8 mv = *(const bf16x8*)&T[nloc * TLD + bl * 32 + q * 8];
#pragma unroll
        for (int k = 0; k < 8; ++k) t += bf2f((ushort_t)mv[k]) * m2f[q * 8 + k];
      }
      tbuf[(size_t)ng * R + (rBase >> 5) + bl] = t;
    }
  }
}

// ---------------------------------------------------------------------------
// K3: chainz — z[a,n] = sum_b M0[a,b,n]*t[b,n]; one wave per 2 samples.
//   lane l reads Mt0 rows l*16..l*16+15 (a = l>>1, b-range = (l&1)*16..+15);
//   pair-reduce via shfl_xor(1).
// ---------------------------------------------------------------------------
__global__ __launch_bounds__(256) void chainz(
    const ushort_t* __restrict__ Mt0, const float* __restrict__ tbuf,
    float* __restrict__ zt)
{
  const int tid = threadIdx.x;
  const int lane = tid & 63, w = tid >> 6;
  const int h = lane & 1, g = lane >> 1;
  const int nb = blockIdx.x * 8 + w * 2;

#pragma unroll
  for (int s = 0; s < 2; ++s) {
    const int n = nb + s;
    const size_t rowbase = (size_t)n * AB + lane * 16;

    float tf[16];
#pragma unroll
    for (int q = 0; q < 4; ++q) {
      float4 v = *(const float4*)&tbuf[(size_t)n * R + h * 16 + q * 4];
      tf[q * 4 + 0] = v.x; tf[q * 4 + 1] = v.y;
      tf[q * 4 + 2] = v.z; tf[q * 4 + 3] = v.w;
    }
    bf16x8 m0a = *(const bf16x8*)&Mt0[rowbase];
    bf16x8 m0b = *(const bf16x8*)&Mt0[rowbase + 8];

    float pz = 0.f;
#pragma unroll
    for (int k = 0; k < 8; ++k) pz += bf2f((ushort_t)m0a[k]) * tf[k];
#pragma unroll
    for (int k = 0; k < 8; ++k) pz += bf2f((ushort_t)m0b[k]) * tf[8 + k];
    pz += __shfl_xor(pz, 1, 64);
    if (h == 0) zt[(size_t)n * R + g] = pz;   // z[a], a = g
  }
}

// ---------------------------------------------------------------------------
// K4: Z[d][n] = sum_a core0[d][a] * zt[n][a]
// ---------------------------------------------------------------------------
__global__ __launch_bounds__(256) void zgemm(
    const float* __restrict__ zt, const float* __restrict__ core0,
    float* __restrict__ out)
{
  __shared__ float c0s[64][R];
  __shared__ float zs[R][132];
  const int n0 = blockIdx.x * 128, d0 = blockIdx.y * 64;
  const int tid = threadIdx.x;
#pragma unroll
  for (int i = 0; i < 4; ++i) {
    int ch = i * 256 + tid;               // 1024 float4 chunks over a
    int nr = ch >> 3, a4 = (ch & 7) * 4;
    float4 v = *(const float4*)&zt[(size_t)(n0 + nr) * R + a4];
    zs[a4 + 0][nr] = v.x; zs[a4 + 1][nr] = v.y;
    zs[a4 + 2][nr] = v.z; zs[a4 + 3][nr] = v.w;
  }
#pragma unroll
  for (int i = 0; i < 2; ++i) {
    int ch = i * 256 + tid;               // 512 float4 chunks of core0 tile
    int rr = ch >> 3, off = (ch & 7) * 4;
    *(float4*)&c0s[rr][off] = *(const float4*)&core0[(size_t)(d0 + rr) * R + off];
  }
  __syncthreads();
  const int tx = tid & 31, ty = tid >> 5;
  float acc[8][4] = {};
  for (int k = 0; k < R; ++k) {
    float4 z4 = *(const float4*)&zs[k][tx * 4];
    float zz[4] = {z4.x, z4.y, z4.z, z4.w};
#pragma unroll
    for (int i = 0; i < 8; ++i) {
      float cv = c0s[ty * 8 + i][k];
#pragma unroll
      for (int jj = 0; jj < 4; ++jj) acc[i][jj] += cv * zz[jj];
    }
  }
#pragma unroll
  for (int i = 0; i < 8; ++i) {
    float4 o = {acc[i][0], acc[i][1], acc[i][2], acc[i][3]};
    *(float4*)&out[(size_t)(d0 + ty * 8 + i) * B + n0 + tx * 4] = o;
  }
}

// ---------------------------------------------------------------------------
extern "C" void kernel_launch(void* const* d_in, const int* in_sizes, int n_in,
                              void* d_out, int out_size, void* d_ws, size_t ws_size,
                              hipStream_t stream)
{
  const float* X0    = (const float*)d_in[0];
  const float* X1    = (const float*)d_in[1];
  const float* X2    = (const float*)d_in[2];
  const float* core0 = (const float*)d_in[3];
  const float* core1 = (const float*)d_in[4];
  const float* core2 = (const float*)d_in[5];
  const float* core3 = (const float*)d_in[6];
  float* out = (float*)d_out;

  char* ws = (char*)d_ws;
  ushort_t* Apack = (ushort_t*)(ws);                       //  2 MiB @ 0
  ushort_t* Xt    = (ushort_t*)(ws + (2u  << 20));         //  8 MiB (2 views)
  ushort_t* Mt0   = (ushort_t*)(ws + (10u << 20));         //  8 MiB
  float*    m2buf = (float*)   (ws + (18u << 20));         //  0.5 MiB
  float*    tbuf  = (float*)   (ws + (19u << 20));         //  0.5 MiB
  float*    zt    = (float*)   (ws + (20u << 20));         //  0.5 MiB

  hipLaunchKernelGGL(prep, dim3(1216), dim3(256), 0, stream,
                     X0, X1, X2, core1, core2, core3, Xt, Apack, m2buf);
  hipLaunchKernelGGL(gemm_mfma, dim3(512), dim3(256), 0, stream,
                     Apack, Xt, m2buf, Mt0, tbuf);
  hipLaunchKernelGGL(chainz, dim3(512), dim3(256), 0, stream, Mt0, tbuf, zt);
  hipLaunchKernelGGL(zgemm, dim3(32, 8), dim3(256), 0, stream, zt, core0, out);
}

// Round 8
// 112.496 us; speedup vs baseline: 1.0946x; 1.0946x over previous
//
#include <hip/hip_runtime.h>

#define D 512      // view dim / d_out
#define B 4096     // batch
#define R 32       // TT rank
#define AB 1024    // R*R rows of reshaped core GEMM

typedef unsigned short ushort_t;
typedef __attribute__((ext_vector_type(8))) short bf16x8;
typedef __attribute__((ext_vector_type(4))) float f32x4;

__device__ __forceinline__ ushort_t f2bf(float f) {
  uint32_t u = __builtin_bit_cast(uint32_t, f);
  u = (u + 0x7FFFu + ((u >> 16) & 1u)) >> 16;   // RNE
  return (ushort_t)u;
}
__device__ __forceinline__ float bf2f(ushort_t h) {
  uint32_t u = ((uint32_t)h) << 16;
  return __builtin_bit_cast(float, u);
}
__device__ __forceinline__ void gload_lds16(const void* g, void* lds) {
  __builtin_amdgcn_global_load_lds(
      (const __attribute__((address_space(1))) unsigned int*)g,
      (__attribute__((address_space(3))) unsigned int*)lds, 16, 0, 0);
}

// ---------------------------------------------------------------------------
// K1: prep — one flat-grid kernel:
//   bid <  1536 : transpose X_v fp32 [d][n] -> Xt bf16 [v][n][d]  (v = bid/512)
//   1536..1599  : pack core1/core2 [a][d][b] -> Apack[j][a*32+b][d]
//   1600..1607  : pack core3 [c][d] -> Apack3[128][512] (rows 32..127 zeroed)
// ---------------------------------------------------------------------------
__global__ __launch_bounds__(256) void prep(
    const float* __restrict__ X0, const float* __restrict__ X1,
    const float* __restrict__ X2, const float* __restrict__ c1,
    const float* __restrict__ c2, const float* __restrict__ c3,
    ushort_t* __restrict__ Xt, ushort_t* __restrict__ Apack,
    ushort_t* __restrict__ Apack3)
{
  __shared__ __align__(16) char smem[33280];
  const int bid = blockIdx.x, tid = threadIdx.x;

  if (bid < 1536) {
    // ---- transpose: 64x64 tile ----
    float (*T)[65] = (float(*)[65])smem;          // [64][65]
    const int v = bid / 512, tile = bid % 512;
    const float* __restrict__ X = (v == 0) ? X0 : ((v == 1) ? X1 : X2);
    ushort_t* __restrict__ O = Xt + (size_t)v * B * D;
    const int n0 = (tile & 63) * 64, d0 = (tile >> 6) * 64;
#pragma unroll
    for (int i = 0; i < 16; ++i) {
      int e = i * 256 + tid;
      T[e >> 6][e & 63] = X[(size_t)(d0 + (e >> 6)) * B + n0 + (e & 63)];
    }
    __syncthreads();
#pragma unroll
    for (int i = 0; i < 2; ++i) {
      int ch = i * 256 + tid;                // 512 chunks
      int nr = ch >> 3, dc = (ch & 7) * 8;
      ushort_t w[8];
#pragma unroll
      for (int q = 0; q < 8; ++q) w[q] = f2bf(T[dc + q][nr]);
      *(bf16x8*)&O[(size_t)(n0 + nr) * D + d0 + dc] = *(bf16x8*)w;
    }
  } else if (bid < 1600) {
    // ---- pack core1/core2 ----
    ushort_t (*T)[D + 8] = (ushort_t(*)[D + 8])smem;   // [32][520]
    const int ja = bid - 1536, j = ja >> 5, a = ja & 31;
    const float* __restrict__ c = j ? c2 : c1;
#pragma unroll
    for (int i = 0; i < 64; ++i) {
      int e = i * 256 + tid;                 // e = d*32 + b, coalesced source
      T[e & 31][e >> 5] = f2bf(c[(size_t)a * (D * R) + e]);
    }
    __syncthreads();
#pragma unroll
    for (int i = 0; i < 8; ++i) {
      int ch = i * 256 + tid;                // 2048 16B chunks
      int b = ch >> 6, off = (ch & 63) * 8;
      ushort_t w[8];
#pragma unroll
      for (int q = 0; q < 8; ++q) w[q] = T[b][off + q];
      *(bf16x8*)&Apack[((size_t)j * AB + a * 32 + b) * D + off] = *(bf16x8*)w;
    }
  } else {
    // ---- pack core3: 16 rows per block ----
    const int r0 = (bid - 1600) * 16;
#pragma unroll
    for (int i = 0; i < 4; ++i) {
      int ch = i * 256 + tid;                // 1024 8-elem chunks = 16x512
      int rr = r0 + (ch >> 6), off = (ch & 63) * 8;
      ushort_t w[8];
      if (rr < R) {
#pragma unroll
        for (int q = 0; q < 8; ++q) w[q] = f2bf(c3[(size_t)rr * D + off + q]);
      } else {
#pragma unroll
        for (int q = 0; q < 8; ++q) w[q] = 0;
      }
      *(bf16x8*)&Apack3[(size_t)rr * D + off] = *(bf16x8*)w;
    }
  }
}

// ---------------------------------------------------------------------------
// K2: MFMA GEMM, 3 "views", XCD-chunked swizzle (544 = 8 XCDs x 68) and
// nb-major work order so the 8 rb-blocks sharing one Xt n-panel are
// consecutive work items on the SAME XCD (panel read once into its L2).
//   wgid<512 : Mt_j[n][row] = sum_d Xt_j[n][d] * Apack_j[row][d], j=wgid>>8
//   wgid>=512: Mt2[n][c]    = sum_d Xt_2[n][d] * Apack3[c][d]   (32 blocks)
// 128x128 tile, BK=32, 4 waves, dbuf global_load_lds, XOR-swizzled LDS,
// LDS-staged epilogue for coalesced [n][row] stores.
// ---------------------------------------------------------------------------
__global__ __launch_bounds__(256) void gemm_mfma(
    const ushort_t* __restrict__ Apack, const ushort_t* __restrict__ Apack3,
    const ushort_t* __restrict__ Xt, ushort_t* __restrict__ Mt,
    ushort_t* __restrict__ Mt2)
{
  __shared__ __align__(16) ushort_t smem[17408];   // 34.8 KB
  ushort_t* As0 = smem;            // Xt tile buf0: [128 n][32 k] swizzled
  ushort_t* As1 = smem + 4096;
  ushort_t* Bs0 = smem + 8192;     // core tile
  ushort_t* Bs1 = smem + 12288;

  // hardware dispatches blockIdx round-robin across 8 XCDs; relabel so each
  // XCD owns a contiguous chunk of 68 work items (bijective: 544 % 8 == 0)
  const int bid0 = blockIdx.x;
  const int bid = ((bid0 & 7) * 68) + (bid0 >> 3);

  int j, rb, nb, ldc;
  const ushort_t *Ag, *Bg;
  ushort_t* C;
  if (bid < 512) {
    j = bid >> 8; int w = bid & 255; nb = w >> 3; rb = w & 7;   // nb-major
    Ag = Xt + (size_t)j * B * D;
    Bg = Apack + (size_t)j * AB * D;
    C  = Mt + (size_t)j * B * AB;  ldc = AB;
  } else {
    j = 2; rb = 0; nb = bid - 512;
    Ag = Xt + (size_t)2 * B * D;
    Bg = Apack3;
    C  = Mt2;  ldc = 128;
  }

  const int tid = threadIdx.x;
  const int lane = tid & 63, wid = tid >> 6;
  const int wr = wid >> 1, wc = wid & 1;
  const int nBase = nb * 128;   // over B=4096
  const int rBase = rb * 128;   // over row dim

  // staging map: 16B unit t -> LDS (row=t>>2, slot u'=t&3); src u = u'^(row&3)
  const int t0 = wid * 128 + lane, t1 = t0 + 64;
  const int r0 = t0 >> 2, u0 = (t0 & 3) ^ (r0 & 3);
  const int r1 = t1 >> 2, u1 = (t1 & 3) ^ (r1 & 3);
  const ushort_t* gA0 = Ag + (size_t)(nBase + r0) * D + u0 * 8;
  const ushort_t* gA1 = Ag + (size_t)(nBase + r1) * D + u1 * 8;
  const ushort_t* gB0 = Bg + (size_t)(rBase + r0) * D + u0 * 8;
  const ushort_t* gB1 = Bg + (size_t)(rBase + r1) * D + u1 * 8;
  const int lq0 = wid * 1024, lq1 = wid * 1024 + 512;   // element offsets

  // frag read offsets: logical (row, u=lane>>4) -> slot u^(row&3)
  int aoff[4], boff[4];
#pragma unroll
  for (int m = 0; m < 4; ++m) {
    int row = wr * 64 + m * 16 + (lane & 15);
    aoff[m] = row * 32 + (((lane >> 4) ^ (row & 3)) * 8);
  }
#pragma unroll
  for (int n = 0; n < 4; ++n) {
    int col = wc * 64 + n * 16 + (lane & 15);
    boff[n] = col * 32 + (((lane >> 4) ^ (col & 3)) * 8);
  }

  f32x4 acc[4][4] = {};

  auto stage = [&](ushort_t* Asb, ushort_t* Bsb, int k0) {
    gload_lds16(gA0 + k0, Asb + lq0);
    gload_lds16(gA1 + k0, Asb + lq1);
    gload_lds16(gB0 + k0, Bsb + lq0);
    gload_lds16(gB1 + k0, Bsb + lq1);
  };
  auto compute = [&](const ushort_t* Asb, const ushort_t* Bsb) {
    bf16x8 a[4], b[4];
#pragma unroll
    for (int m = 0; m < 4; ++m) a[m] = *(const bf16x8*)&Asb[aoff[m]];
#pragma unroll
    for (int n = 0; n < 4; ++n) b[n] = *(const bf16x8*)&Bsb[boff[n]];
#pragma unroll
    for (int m = 0; m < 4; ++m)
#pragma unroll
      for (int n = 0; n < 4; ++n)
        acc[m][n] = __builtin_amdgcn_mfma_f32_16x16x32_bf16(a[m], b[n], acc[m][n], 0, 0, 0);
  };

  stage(As0, Bs0, 0);
  __syncthreads();
#pragma unroll 1
  for (int kp = 0; kp < 8; ++kp) {
    stage(As1, Bs1, kp * 64 + 32);        // prefetch odd tile
    compute(As0, Bs0);
    __syncthreads();
    if (kp < 7) stage(As0, Bs0, kp * 64 + 64);  // prefetch next even tile
    compute(As1, Bs1);
    __syncthreads();
  }

  // epilogue: acc -> LDS tile T[128 n][128 row] (pad 8) -> coalesced stores
#define TLD 136
  ushort_t* T = smem;
  const int qn = (lane >> 4) << 2;
#pragma unroll
  for (int m = 0; m < 4; ++m)
#pragma unroll
    for (int nn = 0; nn < 4; ++nn) {
      int nl = wr * 64 + m * 16 + qn;
      int rl = wc * 64 + nn * 16 + (lane & 15);
#pragma unroll
      for (int r = 0; r < 4; ++r)
        T[(nl + r) * TLD + rl] = f2bf(acc[m][nn][r]);
    }
  __syncthreads();
#pragma unroll
  for (int i = 0; i < 8; ++i) {
    int nl = i * 16 + (tid >> 4);
    int rl = (tid & 15) * 8;
    bf16x8 v = *(const bf16x8*)&T[nl * TLD + rl];
    *(bf16x8*)&C[(size_t)(nBase + nl) * ldc + rBase + rl] = v;
  }
}

// ---------------------------------------------------------------------------
// K3: per-sample chain on transposed M: one wave per sample.
//   lane l holds rows l*16..l*16+15; pair (2g,2g+1) reduces to t[g]/z[g].
//   m2 read from Mt2[n][0..31] (bf16).
// ---------------------------------------------------------------------------
__global__ __launch_bounds__(256) void chain_kernel(
    const ushort_t* __restrict__ Mt, const ushort_t* __restrict__ Mt2,
    float* __restrict__ zt)
{
  __shared__ float ts[4][R];
  const int tid = threadIdx.x;
  const int lane = tid & 63, w = tid >> 6;
  const int h = lane & 1, g = lane >> 1;
  const ushort_t* __restrict__ Mt0 = Mt;                    // [n][1024]
  const ushort_t* __restrict__ Mt1 = Mt + (size_t)B * AB;
  const int nb = blockIdx.x * 8 + w * 2;

#pragma unroll
  for (int s = 0; s < 2; ++s) {
    const int n = nb + s;
    const size_t rowbase = (size_t)n * AB + lane * 16;

    // m2 segment this lane needs: Mt2[n][h*16 .. h*16+15] (bf16)
    bf16x8 m2a = *(const bf16x8*)&Mt2[(size_t)n * 128 + h * 16];
    bf16x8 m2b = *(const bf16x8*)&Mt2[(size_t)n * 128 + h * 16 + 8];

    bf16x8 m1a = *(const bf16x8*)&Mt1[rowbase];
    bf16x8 m1b = *(const bf16x8*)&Mt1[rowbase + 8];
    bf16x8 m0a = *(const bf16x8*)&Mt0[rowbase];
    bf16x8 m0b = *(const bf16x8*)&Mt0[rowbase + 8];

    float pt = 0.f;
#pragma unroll
    for (int k = 0; k < 8; ++k) pt += bf2f((ushort_t)m1a[k]) * bf2f((ushort_t)m2a[k]);
#pragma unroll
    for (int k = 0; k < 8; ++k) pt += bf2f((ushort_t)m1b[k]) * bf2f((ushort_t)m2b[k]);
    pt += __shfl_xor(pt, 1, 64);
    if (h == 0) ts[w][g] = pt;          // t[b] complete, b = g

    float pz = 0.f;
#pragma unroll
    for (int k = 0; k < 8; ++k) pz += bf2f((ushort_t)m0a[k]) * ts[w][h * 16 + k];
#pragma unroll
    for (int k = 0; k < 8; ++k) pz += bf2f((ushort_t)m0b[k]) * ts[w][h * 16 + 8 + k];
    pz += __shfl_xor(pz, 1, 64);
    if (h == 0) zt[(size_t)n * R + g] = pz;   // z[a], a = g
  }
}

// ---------------------------------------------------------------------------
// K4: Z[d][n] = sum_a core0[d][a] * zt[n][a]
// ---------------------------------------------------------------------------
__global__ __launch_bounds__(256) void zgemm(
    const float* __restrict__ zt, const float* __restrict__ core0,
    float* __restrict__ out)
{
  __shared__ float c0s[64][R];
  __shared__ float zs[R][132];
  const int n0 = blockIdx.x * 128, d0 = blockIdx.y * 64;
  const int tid = threadIdx.x;
#pragma unroll
  for (int i = 0; i < 4; ++i) {
    int ch = i * 256 + tid;               // 1024 float4 chunks over a
    int nr = ch >> 3, a4 = (ch & 7) * 4;
    float4 v = *(const float4*)&zt[(size_t)(n0 + nr) * R + a4];
    zs[a4 + 0][nr] = v.x; zs[a4 + 1][nr] = v.y;
    zs[a4 + 2][nr] = v.z; zs[a4 + 3][nr] = v.w;
  }
#pragma unroll
  for (int i = 0; i < 2; ++i) {
    int ch = i * 256 + tid;               // 512 float4 chunks of core0 tile
    int rr = ch >> 3, off = (ch & 7) * 4;
    *(float4*)&c0s[rr][off] = *(const float4*)&core0[(size_t)(d0 + rr) * R + off];
  }
  __syncthreads();
  const int tx = tid & 31, ty = tid >> 5;
  float acc[8][4] = {};
  for (int k = 0; k < R; ++k) {
    float4 z4 = *(const float4*)&zs[k][tx * 4];
    float zz[4] = {z4.x, z4.y, z4.z, z4.w};
#pragma unroll
    for (int i = 0; i < 8; ++i) {
      float cv = c0s[ty * 8 + i][k];
#pragma unroll
      for (int jj = 0; jj < 4; ++jj) acc[i][jj] += cv * zz[jj];
    }
  }
#pragma unroll
  for (int i = 0; i < 8; ++i) {
    float4 o = {acc[i][0], acc[i][1], acc[i][2], acc[i][3]};
    *(float4*)&out[(size_t)(d0 + ty * 8 + i) * B + n0 + tx * 4] = o;
  }
}

// ---------------------------------------------------------------------------
extern "C" void kernel_launch(void* const* d_in, const int* in_sizes, int n_in,
                              void* d_out, int out_size, void* d_ws, size_t ws_size,
                              hipStream_t stream)
{
  const float* X0    = (const float*)d_in[0];
  const float* X1    = (const float*)d_in[1];
  const float* X2    = (const float*)d_in[2];
  const float* core0 = (const float*)d_in[3];
  const float* core1 = (const float*)d_in[4];
  const float* core2 = (const float*)d_in[5];
  const float* core3 = (const float*)d_in[6];
  float* out = (float*)d_out;

  char* ws = (char*)d_ws;
  ushort_t* Apack  = (ushort_t*)(ws);                       //  2 MiB @ 0
  ushort_t* Apack3 = (ushort_t*)(ws + (2u  << 20));         //  128 KiB
  ushort_t* Xt     = (ushort_t*)(ws + (4u  << 20));         //  12 MiB (3 views)
  ushort_t* Mt     = (ushort_t*)(ws + (16u << 20));         //  16 MiB
  ushort_t* Mt2    = (ushort_t*)(ws + (32u << 20));         //   1 MiB
  float*    zt     = (float*)   (ws + (33u << 20));         //  0.5 MiB

  hipLaunchKernelGGL(prep, dim3(1608), dim3(256), 0, stream,
                     X0, X1, X2, core1, core2, core3, Xt, Apack, Apack3);
  hipLaunchKernelGGL(gemm_mfma, dim3(544), dim3(256), 0, stream,
                     Apack, Apack3, Xt, Mt, Mt2);
  hipLaunchKernelGGL(chain_kernel, dim3(512), dim3(256), 0, stream, Mt, Mt2, zt);
  hipLaunchKernelGGL(zgemm, dim3(32, 8), dim3(256), 0, stream, zt, core0, out);
}